// Round 1
// baseline (3677.437 us; speedup 1.0000x reference)
//
#include <hip/hip_runtime.h>

// ---------------------------------------------------------------------------
// UnetMACReconNet: modulated-conv UNet + instance-norm/ReLU + FFT data consistency
// Round 0: correctness-first fp32 implementation.
// ---------------------------------------------------------------------------

#define EPS_IN 1e-5f

// ---------------- conv 3x3, per-sample modulated weights, virtual concat ----
// x1: (B, Ci1, H, W), x2: (B, Ci-Ci1, H, W)  (channel ci reads x1 if ci<Ci1)
// Wt: (Co, Ci, 3, 3), mod: (B, Co, Ci, 3, 3); effective w = Wt*mod[b]
// y: (B, Co, H, W).  No bias (instance-norm cancels it).
template <int TP>
__global__ __launch_bounds__(256) void conv3x3_mod(
    const float* __restrict__ x1, int Ci1,
    const float* __restrict__ x2,
    const float* __restrict__ Wt,
    const float* __restrict__ mod,
    float* __restrict__ y,
    int Ci, int Co, int H, int W)
{
    constexpr int CI_CHUNK = 4;
    constexpr int CO_BLK = 8;
    constexpr int TH = 16 * TP, TW = 16 * TP;
    constexpr int SH = TH + 2, SW = TW + 2;
    __shared__ float s_in[CI_CHUNK][SH][SW];
    __shared__ float s_w[CO_BLK][CI_CHUNK][9];

    const int tid = threadIdx.x;
    const int tx = tid & 15, ty = tid >> 4;
    const int tilesx = W / TW;
    const int tx0 = (blockIdx.x % tilesx) * TW;
    const int ty0 = (blockIdx.x / tilesx) * TH;
    const int co0 = blockIdx.y * CO_BLK;
    const int b = blockIdx.z;
    const size_t HW = (size_t)H * W;
    const int Ci2 = Ci - Ci1;

    float acc[CO_BLK][TP][TP];
#pragma unroll
    for (int co = 0; co < CO_BLK; ++co)
#pragma unroll
        for (int iy = 0; iy < TP; ++iy)
#pragma unroll
            for (int ix = 0; ix < TP; ++ix) acc[co][iy][ix] = 0.f;

    for (int ci0 = 0; ci0 < Ci; ci0 += CI_CHUNK) {
        // stage input slices (zero-padded halo)
        for (int idx = tid; idx < CI_CHUNK * SH * SW; idx += 256) {
            int ci_l = idx / (SH * SW);
            int p = idx % (SH * SW);
            int r = p / SW, c = p % SW;
            int gy = ty0 + r - 1, gx = tx0 + c - 1;
            int ci = ci0 + ci_l;
            float v = 0.f;
            if (ci < Ci && gy >= 0 && gy < H && gx >= 0 && gx < W) {
                const float* src = (ci < Ci1)
                    ? x1 + ((size_t)b * Ci1 + ci) * HW
                    : x2 + ((size_t)b * Ci2 + (ci - Ci1)) * HW;
                v = src[(size_t)gy * W + gx];
            }
            s_in[ci_l][r][c] = v;
        }
        // stage modded weights
        for (int idx = tid; idx < CO_BLK * CI_CHUNK * 9; idx += 256) {
            int k = idx % 9;
            int ci_l = (idx / 9) % CI_CHUNK;
            int co_l = idx / (9 * CI_CHUNK);
            int ci = ci0 + ci_l, co = co0 + co_l;
            float wv = 0.f;
            if (ci < Ci)
                wv = Wt[((size_t)co * Ci + ci) * 9 + k] *
                     mod[(((size_t)b * Co + co) * (size_t)Ci + ci) * 9 + k];
            s_w[co_l][ci_l][k] = wv;
        }
        __syncthreads();

#pragma unroll
        for (int ci_l = 0; ci_l < CI_CHUNK; ++ci_l) {
            float v[TP + 2][TP + 2];
#pragma unroll
            for (int r = 0; r < TP + 2; ++r)
#pragma unroll
                for (int c = 0; c < TP + 2; ++c)
                    v[r][c] = s_in[ci_l][ty * TP + r][tx * TP + c];
#pragma unroll
            for (int co_l = 0; co_l < CO_BLK; ++co_l) {
                float w0 = s_w[co_l][ci_l][0], w1 = s_w[co_l][ci_l][1], w2 = s_w[co_l][ci_l][2];
                float w3 = s_w[co_l][ci_l][3], w4 = s_w[co_l][ci_l][4], w5 = s_w[co_l][ci_l][5];
                float w6 = s_w[co_l][ci_l][6], w7 = s_w[co_l][ci_l][7], w8 = s_w[co_l][ci_l][8];
#pragma unroll
                for (int iy = 0; iy < TP; ++iy)
#pragma unroll
                    for (int ix = 0; ix < TP; ++ix) {
                        float a = acc[co_l][iy][ix];
                        a = fmaf(v[iy][ix], w0, a);
                        a = fmaf(v[iy][ix + 1], w1, a);
                        a = fmaf(v[iy][ix + 2], w2, a);
                        a = fmaf(v[iy + 1][ix], w3, a);
                        a = fmaf(v[iy + 1][ix + 1], w4, a);
                        a = fmaf(v[iy + 1][ix + 2], w5, a);
                        a = fmaf(v[iy + 2][ix], w6, a);
                        a = fmaf(v[iy + 2][ix + 1], w7, a);
                        a = fmaf(v[iy + 2][ix + 2], w8, a);
                        acc[co_l][iy][ix] = a;
                    }
            }
        }
        __syncthreads();
    }

#pragma unroll
    for (int co_l = 0; co_l < CO_BLK; ++co_l)
#pragma unroll
        for (int iy = 0; iy < TP; ++iy)
#pragma unroll
            for (int ix = 0; ix < TP; ++ix) {
                int oy = ty0 + ty * TP + iy, ox = tx0 + tx * TP + ix;
                y[(((size_t)b * Co + co0 + co_l) * H + oy) * W + ox] = acc[co_l][iy][ix];
            }
}

// ---------------- instance-norm stats: one block per (b,c) ------------------
__global__ __launch_bounds__(256) void instat(const float* __restrict__ y,
                                              float2* __restrict__ stats, int HW)
{
    int bc = blockIdx.x;
    const float4* p = reinterpret_cast<const float4*>(y + (size_t)bc * HW);
    int n4 = HW >> 2;
    float s = 0.f, s2 = 0.f;
    for (int i = threadIdx.x; i < n4; i += 256) {
        float4 v = p[i];
        s += v.x + v.y + v.z + v.w;
        s2 += v.x * v.x + v.y * v.y + v.z * v.z + v.w * v.w;
    }
#pragma unroll
    for (int off = 32; off > 0; off >>= 1) {
        s += __shfl_down(s, off);
        s2 += __shfl_down(s2, off);
    }
    __shared__ float as[4], as2[4];
    int lane = threadIdx.x & 63, wid = threadIdx.x >> 6;
    if (lane == 0) { as[wid] = s; as2[wid] = s2; }
    __syncthreads();
    if (threadIdx.x == 0) {
        s = as[0] + as[1] + as[2] + as[3];
        s2 = as2[0] + as2[1] + as2[2] + as2[3];
        float inv = 1.f / (float)HW;
        float mu = s * inv;
        float var = s2 * inv - mu * mu;
        stats[bc] = make_float2(mu, rsqrtf(var + EPS_IN));
    }
}

// ---------------- normalize + relu (in-place, float4) -----------------------
__global__ void norm_relu4(float* __restrict__ y, const float2* __restrict__ stats,
                           int hwshift, int total)
{
    int n4 = total >> 2;
    for (int i = blockIdx.x * blockDim.x + threadIdx.x; i < n4; i += gridDim.x * blockDim.x) {
        int bc = (i << 2) >> hwshift;
        float2 st = stats[bc];
        float4 v = reinterpret_cast<float4*>(y)[i];
        v.x = fmaxf(0.f, (v.x - st.x) * st.y);
        v.y = fmaxf(0.f, (v.y - st.x) * st.y);
        v.z = fmaxf(0.f, (v.z - st.x) * st.y);
        v.w = fmaxf(0.f, (v.w - st.x) * st.y);
        reinterpret_cast<float4*>(y)[i] = v;
    }
}

// ---------------- 2x2 maxpool ------------------------------------------------
__global__ void maxpool2(const float* __restrict__ in, float* __restrict__ out,
                         int s /*log2 Wout*/, int total)
{
    int Wo = 1 << s;
    int Wi = Wo * 2;
    for (int idx = blockIdx.x * blockDim.x + threadIdx.x; idx < total; idx += gridDim.x * blockDim.x) {
        int x = idx & (Wo - 1);
        int yy = (idx >> s) & (Wo - 1);
        int bc = idx >> (2 * s);
        const float* p = in + ((size_t)bc << (2 * s + 2)) + ((size_t)(yy * 2) << (s + 1)) + x * 2;
        out[idx] = fmaxf(fmaxf(p[0], p[1]), fmaxf(p[Wi], p[Wi + 1]));
    }
}

// ---------------- bilinear 2x upsample (half-pixel, edge-clamped) -----------
__global__ void upsample2(const float* __restrict__ in, float* __restrict__ out,
                          int s /*log2 Win*/, int total)
{
    int Win = 1 << s;
    for (int idx = blockIdx.x * blockDim.x + threadIdx.x; idx < total; idx += gridDim.x * blockDim.x) {
        int x = idx & (2 * Win - 1);
        int yy = (idx >> (s + 1)) & (2 * Win - 1);
        int bc = idx >> (2 * s + 2);
        int xk = x >> 1, yk = yy >> 1;
        int xa, xb; float wxa;
        if (x & 1) { xa = xk; xb = (xk + 1 < Win) ? xk + 1 : Win - 1; wxa = 0.75f; }
        else       { xa = (xk > 0) ? xk - 1 : 0; xb = xk; wxa = 0.25f; }
        int ya, yb; float wya;
        if (yy & 1) { ya = yk; yb = (yk + 1 < Win) ? yk + 1 : Win - 1; wya = 0.75f; }
        else        { ya = (yk > 0) ? yk - 1 : 0; yb = yk; wya = 0.25f; }
        const float* p = in + ((size_t)bc << (2 * s));
        float r0 = wxa * p[ya * Win + xa] + (1.f - wxa) * p[ya * Win + xb];
        float r1 = wxa * p[yb * Win + xa] + (1.f - wxa) * p[yb * Win + xb];
        out[idx] = wya * r0 + (1.f - wya) * r1;
    }
}

// ---------------- compose the three 1x1 convs into one 32->1 map ------------
__global__ void eff1x1(const float* __restrict__ w1, const float* __restrict__ b1,
                       const float* __restrict__ w2, const float* __restrict__ b2,
                       const float* __restrict__ w3, const float* __restrict__ b3,
                       float* __restrict__ eff)
{
    int t = threadIdx.x;
    if (t < 32) {
        float s = 0.f;
        for (int k = 0; k < 16; ++k) s += w2[k] * w1[k * 32 + t];
        eff[t] = w3[0] * s;
    }
    if (t == 32) {
        float s = 0.f;
        for (int k = 0; k < 16; ++k) s += w2[k] * b1[k];
        eff[32] = w3[0] * (s + b2[0]) + b3[0];
    }
}

// ---------------- final 32->1 conv + residual add ---------------------------
__global__ void final_pred(const float* __restrict__ act, const float* __restrict__ x0,
                           const float* __restrict__ eff, float* __restrict__ pred)
{
    int idx = blockIdx.x * 256 + threadIdx.x;  // exactly B*65536 threads
    int b = idx >> 16, p = idx & 65535;
    float s = eff[32] + x0[idx];
    const float* a = act + ((size_t)b << 21) + p;
#pragma unroll
    for (int c = 0; c < 32; ++c) s += eff[c] * a[(size_t)c << 16];
    pred[idx] = s;
}

// ---------------- 256-point radix-2 FFT in LDS (one wave) -------------------
__device__ __forceinline__ void fft256(float2* s, int tid, float sign)
{
    __syncthreads();
#pragma unroll
    for (int t = 0; t < 4; ++t) {
        int i = tid + t * 64;
        int r = __brev(i) >> 24;
        if (r > i) { float2 tmp = s[i]; s[i] = s[r]; s[r] = tmp; }
    }
    __syncthreads();
    for (int st = 1; st <= 8; ++st) {
        int m = 1 << st, half = m >> 1;
#pragma unroll
        for (int t = 0; t < 2; ++t) {
            int k = tid + t * 64;
            int g = k >> (st - 1), j = k & (half - 1);
            int i0 = (g << st) + j, i1 = i0 + half;
            float ang = sign * 6.283185307179586f * (float)j / (float)m;
            float sn, cs;
            __sincosf(ang, &sn, &cs);
            float2 a = s[i0], b = s[i1];
            float2 tt = make_float2(b.x * cs - b.y * sn, b.x * sn + b.y * cs);
            s[i0] = make_float2(a.x + tt.x, a.y + tt.y);
            s[i1] = make_float2(a.x - tt.x, a.y - tt.y);
        }
        __syncthreads();
    }
}

__global__ __launch_bounds__(64) void fft_rows_fwd(const float* __restrict__ pred,
                                                   float2* __restrict__ out)
{
    __shared__ float2 s[256];
    int row = blockIdx.x, tid = threadIdx.x;
    const float* p = pred + (size_t)row * 256;
    for (int i = tid; i < 256; i += 64) s[i] = make_float2(p[i], 0.f);
    fft256(s, tid, -1.f);
    float2* o = out + (size_t)row * 256;
    for (int i = tid; i < 256; i += 64) o[i] = s[i];
}

__global__ __launch_bounds__(64) void fft_cols_combine(float2* __restrict__ data,
                                                       const float* __restrict__ ksp,
                                                       const float* __restrict__ mask)
{
    __shared__ float2 s[256];
    int col = blockIdx.x & 255, b = blockIdx.x >> 8;
    int tid = threadIdx.x;
    float2* base = data + (size_t)b * 65536 + col;
    for (int i = tid; i < 256; i += 64) s[i] = base[(size_t)i * 256];
    fft256(s, tid, -1.f);  // now s[k1] = unnormalized 2D FFT column
    for (int i = tid; i < 256; i += 64) {
        size_t mi = ((size_t)b * 256 + i) * 256 + col;
        float m = mask[mi];
        float2 kp = s[i];
        float kr = ksp[mi * 2], ki = ksp[mi * 2 + 1];
        s[i] = make_float2(m * kr + (1.f - m) * kp.x * (1.f / 256.f),
                           m * ki + (1.f - m) * kp.y * (1.f / 256.f));
    }
    fft256(s, tid, 1.f);  // inverse along columns (unnormalized)
    for (int i = tid; i < 256; i += 64) base[(size_t)i * 256] = s[i];
}

__global__ __launch_bounds__(64) void fft_rows_inv(const float2* __restrict__ data,
                                                   float* __restrict__ out)
{
    __shared__ float2 s[256];
    int row = blockIdx.x, tid = threadIdx.x;
    const float2* p = data + (size_t)row * 256;
    for (int i = tid; i < 256; i += 64) s[i] = p[i];
    fft256(s, tid, 1.f);
    float* o = out + (size_t)row * 256;
    for (int i = tid; i < 256; i += 64) o[i] = s[i].x * (1.f / 256.f);
}

// ---------------------------------------------------------------------------
extern "C" void kernel_launch(void* const* d_in, const int* in_sizes, int n_in,
                              void* d_out, int out_size, void* d_ws, size_t ws_size,
                              hipStream_t stream)
{
    (void)in_sizes; (void)n_in; (void)out_size; (void)ws_size;

    const float* x0 = (const float*)d_in[0];
    const float* ksp = (const float*)d_in[1];
    const float* mask = (const float*)d_in[2];
    const float* mod_d[4] = {(const float*)d_in[3], (const float*)d_in[6],
                             (const float*)d_in[9], (const float*)d_in[12]};
    const float* W_d[4] = {(const float*)d_in[4], (const float*)d_in[7],
                           (const float*)d_in[10], (const float*)d_in[13]};
    const float* mod_lat = (const float*)d_in[15];
    const float* W_lat = (const float*)d_in[16];
    const float* mod_u[4] = {(const float*)d_in[18], (const float*)d_in[21],
                             (const float*)d_in[24], (const float*)d_in[27]};
    const float* W_u[4] = {(const float*)d_in[19], (const float*)d_in[22],
                           (const float*)d_in[25], (const float*)d_in[28]};
    const float* w_c1 = (const float*)d_in[30];
    const float* b_c1 = (const float*)d_in[31];
    const float* w_c2 = (const float*)d_in[32];
    const float* b_c2 = (const float*)d_in[33];
    const float* w_c3 = (const float*)d_in[34];
    const float* b_c3 = (const float*)d_in[35];

    float* ws = (float*)d_ws;
    float* bufA = ws;                       // 16777216
    float* bufB = bufA + 16777216;          // 16777216
    float* skip0 = bufB + 16777216;         // 16777216
    float* skip1 = skip0 + 16777216;        // 8388608
    float* skip2 = skip1 + 8388608;         // 4194304
    float* skip3 = skip2 + 4194304;         // 2097152
    float2* cplx = (float2*)(skip3 + 2097152);   // 524288 float2
    float2* stats = cplx + 524288;               // 2048 float2
    float* eff = (float*)(stats + 2048);         // 33 floats

    dim3 blk(256);

    // ---- down 0: 1 -> 32 @256
    conv3x3_mod<2><<<dim3(64, 4, 8), blk, 0, stream>>>(x0, 1, x0, W_d[0], mod_d[0], skip0, 1, 32, 256, 256);
    instat<<<256, blk, 0, stream>>>(skip0, stats, 65536);
    norm_relu4<<<2048, blk, 0, stream>>>(skip0, stats, 16, 16777216);
    maxpool2<<<2048, blk, 0, stream>>>(skip0, bufA, 7, 4194304);

    // ---- down 1: 32 -> 64 @128
    conv3x3_mod<2><<<dim3(16, 8, 8), blk, 0, stream>>>(bufA, 32, bufA, W_d[1], mod_d[1], skip1, 32, 64, 128, 128);
    instat<<<512, blk, 0, stream>>>(skip1, stats, 16384);
    norm_relu4<<<2048, blk, 0, stream>>>(skip1, stats, 14, 8388608);
    maxpool2<<<1024, blk, 0, stream>>>(skip1, bufA, 6, 2097152);

    // ---- down 2: 64 -> 128 @64
    conv3x3_mod<2><<<dim3(4, 16, 8), blk, 0, stream>>>(bufA, 64, bufA, W_d[2], mod_d[2], skip2, 64, 128, 64, 64);
    instat<<<1024, blk, 0, stream>>>(skip2, stats, 4096);
    norm_relu4<<<2048, blk, 0, stream>>>(skip2, stats, 12, 4194304);
    maxpool2<<<512, blk, 0, stream>>>(skip2, bufA, 5, 1048576);

    // ---- down 3: 128 -> 256 @32
    conv3x3_mod<1><<<dim3(4, 32, 8), blk, 0, stream>>>(bufA, 128, bufA, W_d[3], mod_d[3], skip3, 128, 256, 32, 32);
    instat<<<2048, blk, 0, stream>>>(skip3, stats, 1024);
    norm_relu4<<<2048, blk, 0, stream>>>(skip3, stats, 10, 2097152);
    maxpool2<<<256, blk, 0, stream>>>(skip3, bufA, 4, 524288);

    // ---- latent: 256 -> 256 @16
    conv3x3_mod<1><<<dim3(1, 32, 8), blk, 0, stream>>>(bufA, 256, bufA, W_lat, mod_lat, bufB, 256, 256, 16, 16);
    instat<<<2048, blk, 0, stream>>>(bufB, stats, 256);
    norm_relu4<<<512, blk, 0, stream>>>(bufB, stats, 8, 524288);

    // ---- up 0: up(256@16->32) + skip3(256) -> 128 @32
    upsample2<<<2048, blk, 0, stream>>>(bufB, bufA, 4, 2097152);
    conv3x3_mod<1><<<dim3(4, 16, 8), blk, 0, stream>>>(bufA, 256, skip3, W_u[0], mod_u[0], bufB, 512, 128, 32, 32);
    instat<<<1024, blk, 0, stream>>>(bufB, stats, 1024);
    norm_relu4<<<1024, blk, 0, stream>>>(bufB, stats, 10, 1048576);

    // ---- up 1: up(128@32->64) + skip2(128) -> 64 @64
    upsample2<<<2048, blk, 0, stream>>>(bufB, bufA, 5, 4194304);
    conv3x3_mod<2><<<dim3(4, 8, 8), blk, 0, stream>>>(bufA, 128, skip2, W_u[1], mod_u[1], bufB, 256, 64, 64, 64);
    instat<<<512, blk, 0, stream>>>(bufB, stats, 4096);
    norm_relu4<<<2048, blk, 0, stream>>>(bufB, stats, 12, 2097152);

    // ---- up 2: up(64@64->128) + skip1(64) -> 32 @128
    upsample2<<<2048, blk, 0, stream>>>(bufB, bufA, 6, 8388608);
    conv3x3_mod<2><<<dim3(16, 4, 8), blk, 0, stream>>>(bufA, 64, skip1, W_u[2], mod_u[2], bufB, 128, 32, 128, 128);
    instat<<<256, blk, 0, stream>>>(bufB, stats, 16384);
    norm_relu4<<<2048, blk, 0, stream>>>(bufB, stats, 14, 4194304);

    // ---- up 3: up(32@128->256) + skip0(32) -> 32 @256
    upsample2<<<2048, blk, 0, stream>>>(bufB, bufA, 7, 16777216);
    conv3x3_mod<2><<<dim3(64, 4, 8), blk, 0, stream>>>(bufA, 32, skip0, W_u[3], mod_u[3], bufB, 64, 32, 256, 256);
    instat<<<256, blk, 0, stream>>>(bufB, stats, 65536);
    norm_relu4<<<2048, blk, 0, stream>>>(bufB, stats, 16, 16777216);

    // ---- fused 1x1 chain + residual
    eff1x1<<<1, 64, 0, stream>>>(w_c1, b_c1, w_c2, b_c2, w_c3, b_c3, eff);
    final_pred<<<2048, blk, 0, stream>>>(bufB, x0, eff, bufA);

    // ---- FFT data consistency
    fft_rows_fwd<<<2048, 64, 0, stream>>>(bufA, cplx);
    fft_cols_combine<<<2048, 64, 0, stream>>>(cplx, ksp, mask);
    fft_rows_inv<<<2048, 64, 0, stream>>>(cplx, (float*)d_out);
}

// Round 3
// 866.788 us; speedup vs baseline: 4.2426x; 4.2426x over previous
//
#include <hip/hip_runtime.h>

// ---------------------------------------------------------------------------
// UnetMACReconNet: modulated-conv UNet + IN/ReLU + FFT data consistency
// Round 3: bf16 activations everywhere + bf16 MFMA implicit-GEMM convs,
//          JIT per-layer weight modulation into one shared scratch
//          (workspace ~146 MB, was ~280 MB in the crashed R2).
// ---------------------------------------------------------------------------

#define EPS_IN 1e-5f

typedef __attribute__((ext_vector_type(8))) short short8;
typedef __attribute__((ext_vector_type(4))) float f32x4;

__device__ __forceinline__ short f2bf(float f) {
    unsigned u = __float_as_uint(f);
    unsigned r = (u + 0x7fffu + ((u >> 16) & 1u)) >> 16;
    return (short)r;
}
__device__ __forceinline__ float bf2f(short s) {
    return __uint_as_float(((unsigned)(unsigned short)s) << 16);
}

// ---------------- precompute modded bf16 weights: wm[b][tap][co][ci] --------
__global__ void make_wm(const float* __restrict__ W, const float* __restrict__ mod,
                        short* __restrict__ wm, int Co, int Ci)
{
    int idx = blockIdx.x * 256 + threadIdx.x;
    int total = 8 * Co * Ci;
    if (idx >= total) return;
    int ci = idx % Ci;
    int rem = idx / Ci;
    int co = rem % Co;
    int b = rem / Co;
    const float* wp = W + (size_t)(co * Ci + ci) * 9;
    const float* mp = mod + ((size_t)((size_t)b * Co + co) * Ci + ci) * 9;
#pragma unroll
    for (int k = 0; k < 9; ++k)
        wm[(((size_t)(b * 9 + k) * Co + co) * Ci + ci)] = f2bf(wp[k] * mp[k]);
}

// ---------------- MFMA conv3x3, bf16 in/out (Ci, Co multiples of 32) --------
// Block: 256 thr = 4 waves. Tile: 16 wide x (4*R) tall. Co-block 32.
// LDS: s_x[y][x][ci32] bf16 with granule swizzle g ^= (x&3).
template <int R>
__global__ __launch_bounds__(256) void conv3x3_mfma(
    const short* __restrict__ x1, int Ci1,
    const short* __restrict__ x2,
    const short* __restrict__ wm,   // [b][9][Co][Ci] bf16
    short* __restrict__ y,
    int Ci, int Co, int H, int W)
{
    constexpr int TH = 4 * R, TW = 16;
    constexpr int SH = TH + 2, SW = TW + 2;
    __shared__ short s_x[SH][SW][32];

    const int tid = threadIdx.x;
    const int lane = tid & 63, wv = tid >> 6;
    const int m = lane & 15;   // A: co row in 16-group / B & D: pixel col
    const int g = lane >> 4;   // k-group
    const int tilesx = W / TW;
    const int tx0 = (blockIdx.x % tilesx) * TW;
    const int ty0 = (blockIdx.x / tilesx) * TH;
    const int co0 = blockIdx.y * 32;
    const int b = blockIdx.z;
    const size_t HW = (size_t)H * W;
    const int Ci2 = Ci - Ci1;

    f32x4 acc[2][R];
#pragma unroll
    for (int mg = 0; mg < 2; ++mg)
#pragma unroll
        for (int r = 0; r < R; ++r) acc[mg][r] = (f32x4)0.f;

    const short* wmb = wm + (size_t)b * 9 * Co * Ci;

    for (int ci0 = 0; ci0 < Ci; ci0 += 32) {
        __syncthreads();
        // ---- stage 32-ci slice of the (SH x SW) halo tile (bf16 passthrough)
        const short* src = (ci0 < Ci1)
            ? x1 + ((size_t)b * Ci1 + ci0) * HW
            : x2 + ((size_t)b * Ci2 + (ci0 - Ci1)) * HW;
        for (int pos = tid; pos < SH * SW; pos += 256) {
            int yy = pos / SW, xx = pos - yy * SW;
            int gy = ty0 + yy - 1, gx = tx0 + xx - 1;
            bool inb = (gy >= 0) && (gy < H) && (gx >= 0) && (gx < W);
            const short* sp = src + (size_t)gy * W + gx;
#pragma unroll
            for (int gg = 0; gg < 4; ++gg) {
                short8 v;
#pragma unroll
                for (int e = 0; e < 8; ++e)
                    v[e] = inb ? sp[(size_t)(gg * 8 + e) * HW] : (short)0;
                *(short8*)&s_x[yy][xx][(gg ^ (xx & 3)) * 8] = v;
            }
        }
        __syncthreads();

        // ---- 9 taps, K=32 each
#pragma unroll
        for (int t = 0; t < 9; ++t) {
            const int dy = t / 3, dx = t - 3 * (t / 3);
            const short* wr = wmb + (size_t)t * Co * Ci + ci0 + g * 8;
            short8 a0 = *(const short8*)(wr + (size_t)(co0 + m) * Ci);
            short8 a1 = *(const short8*)(wr + (size_t)(co0 + 16 + m) * Ci);
            const int xx = m + dx;
            const int sgo = (g ^ (xx & 3)) * 8;
#pragma unroll
            for (int r = 0; r < R; ++r) {
                int yy = wv * R + r + dy;
                short8 bf = *(const short8*)&s_x[yy][xx][sgo];
                acc[0][r] = __builtin_amdgcn_mfma_f32_16x16x32_bf16(a0, bf, acc[0][r], 0, 0, 0);
                acc[1][r] = __builtin_amdgcn_mfma_f32_16x16x32_bf16(a1, bf, acc[1][r], 0, 0, 0);
            }
        }
    }

    // ---- writeout: D col = pixel (m), row = co-in-group = g*4 + q
    const int ox = tx0 + m;
#pragma unroll
    for (int mg = 0; mg < 2; ++mg)
#pragma unroll
        for (int r = 0; r < R; ++r) {
            int oy = ty0 + wv * R + r;
            short* yp = y + (((size_t)b * Co + co0 + mg * 16 + g * 4) * H + oy) * W + ox;
#pragma unroll
            for (int q = 0; q < 4; ++q)
                yp[(size_t)q * HW] = f2bf(acc[mg][r][q]);
        }
}

// ---------------- d0 conv: Ci=1, Co=32, fp32 input -> bf16 output -----------
__global__ __launch_bounds__(256) void conv_d0(
    const float* __restrict__ x0, const float* __restrict__ W,
    const float* __restrict__ mod, short* __restrict__ y)
{
    __shared__ float s[18][18];
    __shared__ float sw[32][9];
    const int tid = threadIdx.x;
    const int tx = tid & 15, ty = tid >> 4;
    const int tx0 = (blockIdx.x & 15) * 16, ty0 = (blockIdx.x >> 4) * 16;
    const int b = blockIdx.y;
    if (tid < 288) {
        int co = tid / 9, k = tid % 9;
        sw[co][k] = W[co * 9 + k] * mod[((size_t)b * 32 + co) * 9 + k];
    }
    for (int pos = tid; pos < 18 * 18; pos += 256) {
        int yy = pos / 18, xx = pos - yy * 18;
        int gy = ty0 + yy - 1, gx = tx0 + xx - 1;
        bool inb = gy >= 0 && gy < 256 && gx >= 0 && gx < 256;
        s[yy][xx] = inb ? x0[((size_t)b << 16) + gy * 256 + gx] : 0.f;
    }
    __syncthreads();
    float v[3][3];
#pragma unroll
    for (int r = 0; r < 3; ++r)
#pragma unroll
        for (int c = 0; c < 3; ++c) v[r][c] = s[ty + r][tx + c];
    short* yp = y + ((size_t)b * 32) * 65536 + (size_t)(ty0 + ty) * 256 + tx0 + tx;
#pragma unroll
    for (int co = 0; co < 32; ++co) {
        float a = 0.f;
#pragma unroll
        for (int r = 0; r < 3; ++r)
#pragma unroll
            for (int c = 0; c < 3; ++c) a = fmaf(v[r][c], sw[co][r * 3 + c], a);
        yp[(size_t)co * 65536] = f2bf(a);
    }
}

// ---------------- instance-norm stats on bf16: one block per (b,c) ----------
__global__ __launch_bounds__(256) void instat_bf(const short* __restrict__ y,
                                                 float2* __restrict__ stats, int HW)
{
    int bc = blockIdx.x;
    const short8* p = reinterpret_cast<const short8*>(y + (size_t)bc * HW);
    int n8 = HW >> 3;
    float s = 0.f, s2 = 0.f;
    for (int i = threadIdx.x; i < n8; i += 256) {
        short8 v = p[i];
#pragma unroll
        for (int e = 0; e < 8; ++e) {
            float f = bf2f(v[e]);
            s += f; s2 += f * f;
        }
    }
#pragma unroll
    for (int off = 32; off > 0; off >>= 1) {
        s += __shfl_down(s, off);
        s2 += __shfl_down(s2, off);
    }
    __shared__ float as[4], as2[4];
    int lane = threadIdx.x & 63, wid = threadIdx.x >> 6;
    if (lane == 0) { as[wid] = s; as2[wid] = s2; }
    __syncthreads();
    if (threadIdx.x == 0) {
        s = as[0] + as[1] + as[2] + as[3];
        s2 = as2[0] + as2[1] + as2[2] + as2[3];
        float inv = 1.f / (float)HW;
        float mu = s * inv;
        float var = s2 * inv - mu * mu;
        stats[bc] = make_float2(mu, rsqrtf(var + EPS_IN));
    }
}

// ---------------- normalize + relu in-place on bf16 (short8) ----------------
__global__ void norm_relu_bf(short* __restrict__ y, const float2* __restrict__ stats,
                             int hwshift, int total)
{
    int n8 = total >> 3;
    for (int i = blockIdx.x * blockDim.x + threadIdx.x; i < n8; i += gridDim.x * blockDim.x) {
        int bc = (i << 3) >> hwshift;
        float2 st = stats[bc];
        short8 v = reinterpret_cast<short8*>(y)[i];
#pragma unroll
        for (int e = 0; e < 8; ++e) {
            float f = (bf2f(v[e]) - st.x) * st.y;
            v[e] = f2bf(fmaxf(0.f, f));
        }
        reinterpret_cast<short8*>(y)[i] = v;
    }
}

// ---------------- 2x2 maxpool on bf16 ---------------------------------------
__global__ void maxpool_bf(const short* __restrict__ in, short* __restrict__ out,
                           int s /*log2 Wout*/, int total)
{
    int Wo = 1 << s;
    int Wi = Wo * 2;
    for (int idx = blockIdx.x * blockDim.x + threadIdx.x; idx < total; idx += gridDim.x * blockDim.x) {
        int x = idx & (Wo - 1);
        int yy = (idx >> s) & (Wo - 1);
        int bc = idx >> (2 * s);
        const short* p = in + ((size_t)bc << (2 * s + 2)) + ((size_t)(yy * 2) << (s + 1)) + x * 2;
        float m = fmaxf(fmaxf(bf2f(p[0]), bf2f(p[1])), fmaxf(bf2f(p[Wi]), bf2f(p[Wi + 1])));
        out[idx] = f2bf(m);  // exact: f2bf is identity on bf16 values
    }
}

// ---------------- bilinear 2x upsample on bf16 ------------------------------
__global__ void upsample_bf(const short* __restrict__ in, short* __restrict__ out,
                            int s /*log2 Win*/, int total)
{
    int Win = 1 << s;
    for (int idx = blockIdx.x * blockDim.x + threadIdx.x; idx < total; idx += gridDim.x * blockDim.x) {
        int x = idx & (2 * Win - 1);
        int yy = (idx >> (s + 1)) & (2 * Win - 1);
        int bc = idx >> (2 * s + 2);
        int xk = x >> 1, yk = yy >> 1;
        int xa, xb; float wxa;
        if (x & 1) { xa = xk; xb = (xk + 1 < Win) ? xk + 1 : Win - 1; wxa = 0.75f; }
        else       { xa = (xk > 0) ? xk - 1 : 0; xb = xk; wxa = 0.25f; }
        int ya, yb; float wya;
        if (yy & 1) { ya = yk; yb = (yk + 1 < Win) ? yk + 1 : Win - 1; wya = 0.75f; }
        else        { ya = (yk > 0) ? yk - 1 : 0; yb = yk; wya = 0.25f; }
        const short* p = in + ((size_t)bc << (2 * s));
        float r0 = wxa * bf2f(p[ya * Win + xa]) + (1.f - wxa) * bf2f(p[ya * Win + xb]);
        float r1 = wxa * bf2f(p[yb * Win + xa]) + (1.f - wxa) * bf2f(p[yb * Win + xb]);
        out[idx] = f2bf(wya * r0 + (1.f - wya) * r1);
    }
}

// ---------------- compose the three 1x1 convs into one 32->1 map ------------
__global__ void eff1x1(const float* __restrict__ w1, const float* __restrict__ b1,
                       const float* __restrict__ w2, const float* __restrict__ b2,
                       const float* __restrict__ w3, const float* __restrict__ b3,
                       float* __restrict__ eff)
{
    int t = threadIdx.x;
    if (t < 32) {
        float s = 0.f;
        for (int k = 0; k < 16; ++k) s += w2[k] * w1[k * 32 + t];
        eff[t] = w3[0] * s;
    }
    if (t == 32) {
        float s = 0.f;
        for (int k = 0; k < 16; ++k) s += w2[k] * b1[k];
        eff[32] = w3[0] * (s + b2[0]) + b3[0];
    }
}

// ---------------- final 32->1 conv + residual add (bf16 act -> fp32) --------
__global__ void final_pred(const short* __restrict__ act, const float* __restrict__ x0,
                           const float* __restrict__ eff, float* __restrict__ pred)
{
    int idx = blockIdx.x * 256 + threadIdx.x;  // exactly B*65536 threads
    int b = idx >> 16, p = idx & 65535;
    float s = eff[32] + x0[idx];
    const short* a = act + ((size_t)b << 21) + p;
#pragma unroll
    for (int c = 0; c < 32; ++c) s += eff[c] * bf2f(a[(size_t)c << 16]);
    pred[idx] = s;
}

// ---------------- 256-point radix-2 FFT in LDS (one wave) -------------------
__device__ __forceinline__ void fft256(float2* s, int tid, float sign)
{
    __syncthreads();
#pragma unroll
    for (int t = 0; t < 4; ++t) {
        int i = tid + t * 64;
        int r = __brev(i) >> 24;
        if (r > i) { float2 tmp = s[i]; s[i] = s[r]; s[r] = tmp; }
    }
    __syncthreads();
    for (int st = 1; st <= 8; ++st) {
        int m = 1 << st, half = m >> 1;
#pragma unroll
        for (int t = 0; t < 2; ++t) {
            int k = tid + t * 64;
            int g = k >> (st - 1), j = k & (half - 1);
            int i0 = (g << st) + j, i1 = i0 + half;
            float ang = sign * 6.283185307179586f * (float)j / (float)m;
            float sn, cs;
            __sincosf(ang, &sn, &cs);
            float2 a = s[i0], b = s[i1];
            float2 tt = make_float2(b.x * cs - b.y * sn, b.x * sn + b.y * cs);
            s[i0] = make_float2(a.x + tt.x, a.y + tt.y);
            s[i1] = make_float2(a.x - tt.x, a.y - tt.y);
        }
        __syncthreads();
    }
}

__global__ __launch_bounds__(64) void fft_rows_fwd(const float* __restrict__ pred,
                                                   float2* __restrict__ out)
{
    __shared__ float2 s[256];
    int row = blockIdx.x, tid = threadIdx.x;
    const float* p = pred + (size_t)row * 256;
    for (int i = tid; i < 256; i += 64) s[i] = make_float2(p[i], 0.f);
    fft256(s, tid, -1.f);
    float2* o = out + (size_t)row * 256;
    for (int i = tid; i < 256; i += 64) o[i] = s[i];
}

__global__ __launch_bounds__(64) void fft_cols_combine(float2* __restrict__ data,
                                                       const float* __restrict__ ksp,
                                                       const float* __restrict__ mask)
{
    __shared__ float2 s[256];
    int col = blockIdx.x & 255, b = blockIdx.x >> 8;
    int tid = threadIdx.x;
    float2* base = data + (size_t)b * 65536 + col;
    for (int i = tid; i < 256; i += 64) s[i] = base[(size_t)i * 256];
    fft256(s, tid, -1.f);
    for (int i = tid; i < 256; i += 64) {
        size_t mi = ((size_t)b * 256 + i) * 256 + col;
        float m = mask[mi];
        float2 kp = s[i];
        float kr = ksp[mi * 2], ki = ksp[mi * 2 + 1];
        s[i] = make_float2(m * kr + (1.f - m) * kp.x * (1.f / 256.f),
                           m * ki + (1.f - m) * kp.y * (1.f / 256.f));
    }
    fft256(s, tid, 1.f);
    for (int i = tid; i < 256; i += 64) base[(size_t)i * 256] = s[i];
}

__global__ __launch_bounds__(64) void fft_rows_inv(const float2* __restrict__ data,
                                                   float* __restrict__ out)
{
    __shared__ float2 s[256];
    int row = blockIdx.x, tid = threadIdx.x;
    const float2* p = data + (size_t)row * 256;
    for (int i = tid; i < 256; i += 64) s[i] = p[i];
    fft256(s, tid, 1.f);
    float* o = out + (size_t)row * 256;
    for (int i = tid; i < 256; i += 64) o[i] = s[i].x * (1.f / 256.f);
}

// ---------------------------------------------------------------------------
extern "C" void kernel_launch(void* const* d_in, const int* in_sizes, int n_in,
                              void* d_out, int out_size, void* d_ws, size_t ws_size,
                              hipStream_t stream)
{
    (void)in_sizes; (void)n_in; (void)out_size; (void)ws_size;

    const float* x0 = (const float*)d_in[0];
    const float* ksp = (const float*)d_in[1];
    const float* mask = (const float*)d_in[2];
    const float* mod_d[4] = {(const float*)d_in[3], (const float*)d_in[6],
                             (const float*)d_in[9], (const float*)d_in[12]};
    const float* W_d[4] = {(const float*)d_in[4], (const float*)d_in[7],
                           (const float*)d_in[10], (const float*)d_in[13]};
    const float* mod_lat = (const float*)d_in[15];
    const float* W_lat = (const float*)d_in[16];
    const float* mod_u[4] = {(const float*)d_in[18], (const float*)d_in[21],
                             (const float*)d_in[24], (const float*)d_in[27]};
    const float* W_u[4] = {(const float*)d_in[19], (const float*)d_in[22],
                           (const float*)d_in[25], (const float*)d_in[28]};
    const float* w_c1 = (const float*)d_in[30];
    const float* b_c1 = (const float*)d_in[31];
    const float* w_c2 = (const float*)d_in[32];
    const float* b_c2 = (const float*)d_in[33];
    const float* w_c3 = (const float*)d_in[34];
    const float* b_c3 = (const float*)d_in[35];

    // ---- workspace layout (bf16 activations), ~146 MB total
    short* sA  = (short*)d_ws;          // 16,777,216 sh (max act: 8x32x256x256)
    short* sB  = sA + 16777216;         // 16,777,216 sh
    short* sk0 = sB + 16777216;         // 16,777,216 sh (8,32,256,256)
    short* sk1 = sk0 + 16777216;        //  8,388,608 sh (8,64,128,128)
    short* sk2 = sk1 + 8388608;         //  4,194,304 sh (8,128,64,64)
    short* sk3 = sk2 + 4194304;         //  2,097,152 sh (8,256,32,32)
    short* wm  = sk3 + 2097152;         //  4,718,592 sh (shared JIT wm scratch)
    float* pred = (float*)(wm + 4718592);      // 524,288 f
    float2* cplx = (float2*)(pred + 524288);   // 524,288 f2
    float2* stats = cplx + 524288;             // 2,048 f2
    float* eff = (float*)(stats + 2048);       // 64 f

    dim3 blk(256);

    // ---- down 0: 1 -> 32 @256 (fp32 input, bf16 out)
    conv_d0<<<dim3(256, 8), blk, 0, stream>>>(x0, W_d[0], mod_d[0], sk0);
    instat_bf<<<256, blk, 0, stream>>>(sk0, stats, 65536);
    norm_relu_bf<<<2048, blk, 0, stream>>>(sk0, stats, 16, 16777216);
    maxpool_bf<<<2048, blk, 0, stream>>>(sk0, sA, 7, 4194304);

    // ---- down 1: 32 -> 64 @128
    make_wm<<<(8 * 64 * 32 + 255) / 256, blk, 0, stream>>>(W_d[1], mod_d[1], wm, 64, 32);
    conv3x3_mfma<8><<<dim3(32, 2, 8), blk, 0, stream>>>(sA, 32, sA, wm, sk1, 32, 64, 128, 128);
    instat_bf<<<512, blk, 0, stream>>>(sk1, stats, 16384);
    norm_relu_bf<<<2048, blk, 0, stream>>>(sk1, stats, 14, 8388608);
    maxpool_bf<<<1024, blk, 0, stream>>>(sk1, sA, 6, 2097152);

    // ---- down 2: 64 -> 128 @64
    make_wm<<<(8 * 128 * 64 + 255) / 256, blk, 0, stream>>>(W_d[2], mod_d[2], wm, 128, 64);
    conv3x3_mfma<8><<<dim3(8, 4, 8), blk, 0, stream>>>(sA, 64, sA, wm, sk2, 64, 128, 64, 64);
    instat_bf<<<1024, blk, 0, stream>>>(sk2, stats, 4096);
    norm_relu_bf<<<2048, blk, 0, stream>>>(sk2, stats, 12, 4194304);
    maxpool_bf<<<512, blk, 0, stream>>>(sk2, sA, 5, 1048576);

    // ---- down 3: 128 -> 256 @32
    make_wm<<<(8 * 256 * 128 + 255) / 256, blk, 0, stream>>>(W_d[3], mod_d[3], wm, 256, 128);
    conv3x3_mfma<8><<<dim3(2, 8, 8), blk, 0, stream>>>(sA, 128, sA, wm, sk3, 128, 256, 32, 32);
    instat_bf<<<2048, blk, 0, stream>>>(sk3, stats, 1024);
    norm_relu_bf<<<2048, blk, 0, stream>>>(sk3, stats, 10, 2097152);
    maxpool_bf<<<256, blk, 0, stream>>>(sk3, sA, 4, 524288);

    // ---- latent: 256 -> 256 @16
    make_wm<<<(8 * 256 * 256 + 255) / 256, blk, 0, stream>>>(W_lat, mod_lat, wm, 256, 256);
    conv3x3_mfma<4><<<dim3(1, 8, 8), blk, 0, stream>>>(sA, 256, sA, wm, sB, 256, 256, 16, 16);
    instat_bf<<<2048, blk, 0, stream>>>(sB, stats, 256);
    norm_relu_bf<<<512, blk, 0, stream>>>(sB, stats, 8, 524288);

    // ---- up 0: up(256@16->32) ++ skip3(256) -> 128 @32
    upsample_bf<<<2048, blk, 0, stream>>>(sB, sA, 4, 2097152);
    make_wm<<<(8 * 128 * 512 + 255) / 256, blk, 0, stream>>>(W_u[0], mod_u[0], wm, 128, 512);
    conv3x3_mfma<8><<<dim3(2, 4, 8), blk, 0, stream>>>(sA, 256, sk3, wm, sB, 512, 128, 32, 32);
    instat_bf<<<1024, blk, 0, stream>>>(sB, stats, 1024);
    norm_relu_bf<<<1024, blk, 0, stream>>>(sB, stats, 10, 1048576);

    // ---- up 1: up(128@32->64) ++ skip2(128) -> 64 @64
    upsample_bf<<<2048, blk, 0, stream>>>(sB, sA, 5, 4194304);
    make_wm<<<(8 * 64 * 256 + 255) / 256, blk, 0, stream>>>(W_u[1], mod_u[1], wm, 64, 256);
    conv3x3_mfma<8><<<dim3(8, 2, 8), blk, 0, stream>>>(sA, 128, sk2, wm, sB, 256, 64, 64, 64);
    instat_bf<<<512, blk, 0, stream>>>(sB, stats, 4096);
    norm_relu_bf<<<2048, blk, 0, stream>>>(sB, stats, 12, 2097152);

    // ---- up 2: up(64@64->128) ++ skip1(64) -> 32 @128
    upsample_bf<<<2048, blk, 0, stream>>>(sB, sA, 6, 8388608);
    make_wm<<<(8 * 32 * 128 + 255) / 256, blk, 0, stream>>>(W_u[2], mod_u[2], wm, 32, 128);
    conv3x3_mfma<8><<<dim3(32, 1, 8), blk, 0, stream>>>(sA, 64, sk1, wm, sB, 128, 32, 128, 128);
    instat_bf<<<256, blk, 0, stream>>>(sB, stats, 16384);
    norm_relu_bf<<<2048, blk, 0, stream>>>(sB, stats, 14, 4194304);

    // ---- up 3: up(32@128->256) ++ skip0(32) -> 32 @256
    upsample_bf<<<2048, blk, 0, stream>>>(sB, sA, 7, 16777216);
    make_wm<<<(8 * 32 * 64 + 255) / 256, blk, 0, stream>>>(W_u[3], mod_u[3], wm, 32, 64);
    conv3x3_mfma<8><<<dim3(128, 1, 8), blk, 0, stream>>>(sA, 32, sk0, wm, sB, 64, 32, 256, 256);
    instat_bf<<<256, blk, 0, stream>>>(sB, stats, 65536);
    norm_relu_bf<<<2048, blk, 0, stream>>>(sB, stats, 16, 16777216);

    // ---- fused 1x1 chain + residual
    eff1x1<<<1, 64, 0, stream>>>(w_c1, b_c1, w_c2, b_c2, w_c3, b_c3, eff);
    final_pred<<<2048, blk, 0, stream>>>(sB, x0, eff, pred);

    // ---- FFT data consistency
    fft_rows_fwd<<<2048, 64, 0, stream>>>(pred, cplx);
    fft_cols_combine<<<2048, 64, 0, stream>>>(cplx, ksp, mask);
    fft_rows_inv<<<2048, 64, 0, stream>>>(cplx, (float*)d_out);
}

// Round 4
// 543.807 us; speedup vs baseline: 6.7624x; 1.5939x over previous
//
#include <hip/hip_runtime.h>

// ---------------------------------------------------------------------------
// UnetMACReconNet: modulated-conv UNet + IN/ReLU + FFT data consistency
// Round 4: channels-last bf16 activations, occupancy-tuned MFMA convs,
//          IN-stats fused into conv epilogue (global fp32 atomics).
// ---------------------------------------------------------------------------

#define EPS_IN 1e-5f

typedef __attribute__((ext_vector_type(8))) short short8;
typedef __attribute__((ext_vector_type(4))) short short4_t;
typedef __attribute__((ext_vector_type(4))) float f32x4;

__device__ __forceinline__ short f2bf(float f) {
    unsigned u = __float_as_uint(f);
    unsigned r = (u + 0x7fffu + ((u >> 16) & 1u)) >> 16;
    return (short)r;
}
__device__ __forceinline__ float bf2f(short s) {
    return __uint_as_float(((unsigned)(unsigned short)s) << 16);
}

// ---------------- zero the stat accumulators --------------------------------
__global__ void zero_f(float* __restrict__ p, int n)
{
    int i = blockIdx.x * 256 + threadIdx.x;
    if (i < n) p[i] = 0.f;
}

// ---------------- precompute modded bf16 weights: wm[b][tap][co][ci] --------
__global__ void make_wm(const float* __restrict__ W, const float* __restrict__ mod,
                        short* __restrict__ wm, int Co, int Ci)
{
    int idx = blockIdx.x * 256 + threadIdx.x;
    int total = 8 * Co * Ci;
    if (idx >= total) return;
    int ci = idx % Ci;
    int rem = idx / Ci;
    int co = rem % Co;
    int b = rem / Co;
    const float* wp = W + (size_t)(co * Ci + ci) * 9;
    const float* mp = mod + ((size_t)((size_t)b * Co + co) * Ci + ci) * 9;
#pragma unroll
    for (int k = 0; k < 9; ++k)
        wm[(((size_t)(b * 9 + k) * Co + co) * Ci + ci)] = f2bf(wp[k] * mp[k]);
}

// ---------------- MFMA conv3x3, channels-last, fused IN-stat accumulation ---
// Block: 4 waves; wave wv handles rows [wv*VR, wv*VR+VR), NCOG co-groups of 16.
// x layout: [b][y][x][c] bf16.  y layout: [b][y][x][co] bf16.
// stats[b*Co + co] accumulates (sum, sumsq) of fp32 conv outputs via atomics.
template <int VR, int NCOG>
__global__ __launch_bounds__(256) void conv3x3_cl(
    const short* __restrict__ x1, int Ci1,
    const short* __restrict__ x2,
    const short* __restrict__ wm,   // [b][9][Co][Ci] bf16
    short* __restrict__ y,
    float2* __restrict__ stats,
    int Ci, int Co, int H, int W)
{
    constexpr int TH = 4 * VR, SH = TH + 2, SW = 18;
    __shared__ short s_x[SH][SW][32];
    __shared__ float s_red[4][4][NCOG][4][2];

    const int tid = threadIdx.x;
    const int lane = tid & 63, wv = tid >> 6;
    const int m = lane & 15, g = lane >> 4;
    const int tilesx = W >> 4;
    const int tx0 = (blockIdx.x % tilesx) * 16;
    const int ty0 = (blockIdx.x / tilesx) * TH;
    const int co0 = blockIdx.y * (16 * NCOG);
    const int b = blockIdx.z;
    const int Ci2 = Ci - Ci1;

    f32x4 acc[NCOG][VR];
#pragma unroll
    for (int cg = 0; cg < NCOG; ++cg)
#pragma unroll
        for (int r = 0; r < VR; ++r) acc[cg][r] = (f32x4)0.f;

    const short* wmb = wm + (size_t)b * 9 * Co * Ci;

    for (int ci0 = 0; ci0 < Ci; ci0 += 32) {
        const short* src; int C, cb;
        if (ci0 < Ci1) { src = x1 + (size_t)b * H * W * Ci1; C = Ci1; cb = ci0; }
        else           { src = x2 + (size_t)b * H * W * Ci2; C = Ci2; cb = ci0 - Ci1; }
        __syncthreads();
        for (int idx = tid; idx < SH * SW * 4; idx += 256) {
            int gg = idx & 3, pos = idx >> 2;
            int yy = pos / SW, xx = pos - yy * SW;
            int gy = ty0 + yy - 1, gx = tx0 + xx - 1;
            short8 v = (short8)0;
            if (gy >= 0 && gy < H && gx >= 0 && gx < W)
                v = *(const short8*)(src + ((size_t)gy * W + gx) * C + cb + gg * 8);
            *(short8*)&s_x[yy][xx][(gg ^ (xx & 3)) * 8] = v;
        }
        __syncthreads();
#pragma unroll
        for (int t = 0; t < 9; ++t) {
            const int dy = t / 3, dx = t - 3 * (t / 3);
            const short* wr = wmb + ((size_t)t * Co + co0) * Ci + ci0 + g * 8;
            short8 a[NCOG];
#pragma unroll
            for (int cg = 0; cg < NCOG; ++cg)
                a[cg] = *(const short8*)(wr + (size_t)(cg * 16 + m) * Ci);
            const int xx = m + dx;
            const int sgo = (g ^ (xx & 3)) * 8;
#pragma unroll
            for (int r = 0; r < VR; ++r) {
                short8 bf = *(const short8*)&s_x[wv * VR + r + dy][xx][sgo];
#pragma unroll
                for (int cg = 0; cg < NCOG; ++cg)
                    acc[cg][r] = __builtin_amdgcn_mfma_f32_16x16x32_bf16(a[cg], bf, acc[cg][r], 0, 0, 0);
            }
        }
    }

    // ---- writeout (CL: 4 consecutive co per lane) + fused stats
    const int ox = tx0 + m;
#pragma unroll
    for (int cg = 0; cg < NCOG; ++cg)
#pragma unroll
        for (int r = 0; r < VR; ++r) {
            int oy = ty0 + wv * VR + r;
            short4_t o;
#pragma unroll
            for (int q = 0; q < 4; ++q) o[q] = f2bf(acc[cg][r][q]);
            *(short4_t*)(y + (((size_t)b * H + oy) * W + ox) * Co + co0 + cg * 16 + g * 4) = o;
        }

#pragma unroll
    for (int cg = 0; cg < NCOG; ++cg)
#pragma unroll
        for (int q = 0; q < 4; ++q) {
            float s = 0.f, s2 = 0.f;
#pragma unroll
            for (int r = 0; r < VR; ++r) { float v = acc[cg][r][q]; s += v; s2 += v * v; }
#pragma unroll
            for (int msk = 1; msk < 16; msk <<= 1) { s += __shfl_xor(s, msk); s2 += __shfl_xor(s2, msk); }
            if (m == 0) { s_red[wv][g][cg][q][0] = s; s_red[wv][g][cg][q][1] = s2; }
        }
    __syncthreads();
    for (int i = tid; i < 16 * NCOG; i += 256) {
        int q = i & 3, gg = (i >> 2) & 3, cg = i >> 4;
        float S = 0.f, S2 = 0.f;
#pragma unroll
        for (int w = 0; w < 4; ++w) { S += s_red[w][gg][cg][q][0]; S2 += s_red[w][gg][cg][q][1]; }
        float* sp = (float*)&stats[(size_t)b * Co + co0 + i];
        atomicAdd(sp, S); atomicAdd(sp + 1, S2);
    }
}

// ---------------- d0 conv: Ci=1, Co=32, fp32 NCHW in -> CL bf16 out ---------
__global__ __launch_bounds__(256) void conv_d0_cl(
    const float* __restrict__ x0, const float* __restrict__ W,
    const float* __restrict__ mod, short* __restrict__ y,
    float2* __restrict__ stats)
{
    __shared__ float s[18][18];
    __shared__ float sw[32][9];
    __shared__ float s_red[4][32][2];
    const int tid = threadIdx.x;
    const int tx = tid & 15, ty = tid >> 4;
    const int tx0 = (blockIdx.x & 15) * 16, ty0 = (blockIdx.x >> 4) * 16;
    const int b = blockIdx.y;
    if (tid < 288) sw[tid / 9][tid % 9] = W[tid] * mod[b * 288 + tid];
    for (int pos = tid; pos < 18 * 18; pos += 256) {
        int yy = pos / 18, xx = pos - yy * 18;
        int gy = ty0 + yy - 1, gx = tx0 + xx - 1;
        bool inb = gy >= 0 && gy < 256 && gx >= 0 && gx < 256;
        s[yy][xx] = inb ? x0[((size_t)b << 16) + gy * 256 + gx] : 0.f;
    }
    __syncthreads();
    float v[3][3];
#pragma unroll
    for (int r = 0; r < 3; ++r)
#pragma unroll
        for (int c = 0; c < 3; ++c) v[r][c] = s[ty + r][tx + c];
    float vals[32];
#pragma unroll
    for (int co = 0; co < 32; ++co) {
        float a = 0.f;
#pragma unroll
        for (int r = 0; r < 3; ++r)
#pragma unroll
            for (int c = 0; c < 3; ++c) a = fmaf(v[r][c], sw[co][r * 3 + c], a);
        vals[co] = a;
    }
    short* yp = y + (((size_t)b * 256 + ty0 + ty) * 256 + tx0 + tx) * 32;
#pragma unroll
    for (int j = 0; j < 4; ++j) {
        short8 o;
#pragma unroll
        for (int e = 0; e < 8; ++e) o[e] = f2bf(vals[j * 8 + e]);
        *(short8*)(yp + j * 8) = o;
    }
    const int lane = tid & 63, wv = tid >> 6;
#pragma unroll
    for (int co = 0; co < 32; ++co) {
        float sm = vals[co], s2 = vals[co] * vals[co];
#pragma unroll
        for (int off = 32; off > 0; off >>= 1) { sm += __shfl_down(sm, off); s2 += __shfl_down(s2, off); }
        if (lane == 0) { s_red[wv][co][0] = sm; s_red[wv][co][1] = s2; }
    }
    __syncthreads();
    if (tid < 32) {
        float S = 0.f, S2 = 0.f;
#pragma unroll
        for (int w = 0; w < 4; ++w) { S += s_red[w][tid][0]; S2 += s_red[w][tid][1]; }
        float* sp = (float*)&stats[(size_t)b * 32 + tid];
        atomicAdd(sp, S); atomicAdd(sp + 1, S2);
    }
}

// ---------------- normalize + relu in-place, channels-last ------------------
__global__ __launch_bounds__(256) void norm_relu_cl(
    short* __restrict__ y, const float2* __restrict__ stats,
    int Co, int n8 /*HW*Co/8 per b*/, float invHW)
{
    __shared__ float2 st[256];
    const int b = blockIdx.y;
    for (int i = threadIdx.x; i < Co; i += 256) {
        float2 v = stats[(size_t)b * Co + i];
        float mu = v.x * invHW;
        float var = v.y * invHW - mu * mu;
        st[i] = make_float2(mu, rsqrtf(var + EPS_IN));
    }
    __syncthreads();
    const int c8m = (Co >> 3) - 1;
    short8* base = (short8*)(y + (size_t)b * n8 * 8);
    for (int i = blockIdx.x * 256 + threadIdx.x; i < n8; i += gridDim.x * 256) {
        int c0 = (i & c8m) * 8;
        short8 v = base[i];
#pragma unroll
        for (int e = 0; e < 8; ++e) {
            float2 s = st[c0 + e];
            v[e] = f2bf(fmaxf(0.f, (bf2f(v[e]) - s.x) * s.y));
        }
        base[i] = v;
    }
}

// ---------------- 2x2 maxpool, channels-last --------------------------------
__global__ void maxpool_cl(const short* __restrict__ in, short* __restrict__ out,
                           int c8s, int ws, int hs, int total8)
{
    const int C = 8 << c8s;
    for (int idx = blockIdx.x * 256 + threadIdx.x; idx < total8; idx += gridDim.x * 256) {
        int c8 = idx & ((1 << c8s) - 1);
        int p = idx >> c8s;
        int x = p & ((1 << ws) - 1);
        int yy = (p >> ws) & ((1 << hs) - 1);
        int b = p >> (ws + hs);
        const short* ip = in + (((size_t)b * (2 << hs) + 2 * yy) * (2 << ws) + 2 * x) * C + c8 * 8;
        size_t rs = (size_t)(2 << ws) * C;
        short8 v0 = *(const short8*)ip, v1 = *(const short8*)(ip + C);
        short8 v2 = *(const short8*)(ip + rs), v3 = *(const short8*)(ip + rs + C);
        short8 o;
#pragma unroll
        for (int e = 0; e < 8; ++e)
            o[e] = f2bf(fmaxf(fmaxf(bf2f(v0[e]), bf2f(v1[e])), fmaxf(bf2f(v2[e]), bf2f(v3[e]))));
        *(short8*)(out + (size_t)idx * 8) = o;
    }
}

// ---------------- bilinear 2x upsample, channels-last -----------------------
__global__ void upsample_cl(const short* __restrict__ in, short* __restrict__ out,
                            int c8s, int wsi, int hsi, int total8)
{
    const int C = 8 << c8s;
    const int Win = 1 << wsi, Hin = 1 << hsi;
    for (int idx = blockIdx.x * 256 + threadIdx.x; idx < total8; idx += gridDim.x * 256) {
        int c8 = idx & ((1 << c8s) - 1);
        int p = idx >> c8s;
        int x = p & (2 * Win - 1);
        int yy = (p >> (wsi + 1)) & (2 * Hin - 1);
        int b = p >> (wsi + 1 + hsi + 1);
        int xk = x >> 1, yk = yy >> 1;
        int xa, xb; float wxa;
        if (x & 1) { xa = xk; xb = (xk + 1 < Win) ? xk + 1 : Win - 1; wxa = 0.75f; }
        else       { xa = (xk > 0) ? xk - 1 : 0; xb = xk; wxa = 0.25f; }
        int ya, yb; float wya;
        if (yy & 1) { ya = yk; yb = (yk + 1 < Hin) ? yk + 1 : Hin - 1; wya = 0.75f; }
        else        { ya = (yk > 0) ? yk - 1 : 0; yb = yk; wya = 0.25f; }
        const short* ib = in + (size_t)b * Hin * Win * C + c8 * 8;
        short8 vaa = *(const short8*)(ib + ((size_t)ya * Win + xa) * C);
        short8 vab = *(const short8*)(ib + ((size_t)ya * Win + xb) * C);
        short8 vba = *(const short8*)(ib + ((size_t)yb * Win + xa) * C);
        short8 vbb = *(const short8*)(ib + ((size_t)yb * Win + xb) * C);
        short8 o;
#pragma unroll
        for (int e = 0; e < 8; ++e) {
            float r0 = wxa * bf2f(vaa[e]) + (1.f - wxa) * bf2f(vab[e]);
            float r1 = wxa * bf2f(vba[e]) + (1.f - wxa) * bf2f(vbb[e]);
            o[e] = f2bf(wya * r0 + (1.f - wya) * r1);
        }
        *(short8*)(out + (size_t)idx * 8) = o;
    }
}

// ---------------- compose the three 1x1 convs into one 32->1 map ------------
__global__ void eff1x1(const float* __restrict__ w1, const float* __restrict__ b1,
                       const float* __restrict__ w2, const float* __restrict__ b2,
                       const float* __restrict__ w3, const float* __restrict__ b3,
                       float* __restrict__ eff)
{
    int t = threadIdx.x;
    if (t < 32) {
        float s = 0.f;
        for (int k = 0; k < 16; ++k) s += w2[k] * w1[k * 32 + t];
        eff[t] = w3[0] * s;
    }
    if (t == 32) {
        float s = 0.f;
        for (int k = 0; k < 16; ++k) s += w2[k] * b1[k];
        eff[32] = w3[0] * (s + b2[0]) + b3[0];
    }
}

// ---------------- final 32->1 conv + residual (CL bf16 -> fp32) -------------
__global__ void final_pred_cl(const short* __restrict__ act, const float* __restrict__ x0,
                              const float* __restrict__ eff, float* __restrict__ pred)
{
    int idx = blockIdx.x * 256 + threadIdx.x;  // exactly B*65536 threads
    const short8* a = (const short8*)(act + (size_t)idx * 32);
    float s = eff[32] + x0[idx];
#pragma unroll
    for (int j = 0; j < 4; ++j) {
        short8 v = a[j];
#pragma unroll
        for (int e = 0; e < 8; ++e) s += eff[j * 8 + e] * bf2f(v[e]);
    }
    pred[idx] = s;
}

// ---------------- 256-point radix-2 FFT in LDS (one wave) -------------------
__device__ __forceinline__ void fft256(float2* s, int tid, float sign)
{
    __syncthreads();
#pragma unroll
    for (int t = 0; t < 4; ++t) {
        int i = tid + t * 64;
        int r = __brev(i) >> 24;
        if (r > i) { float2 tmp = s[i]; s[i] = s[r]; s[r] = tmp; }
    }
    __syncthreads();
    for (int st = 1; st <= 8; ++st) {
        int m = 1 << st, half = m >> 1;
#pragma unroll
        for (int t = 0; t < 2; ++t) {
            int k = tid + t * 64;
            int g = k >> (st - 1), j = k & (half - 1);
            int i0 = (g << st) + j, i1 = i0 + half;
            float ang = sign * 6.283185307179586f * (float)j / (float)m;
            float sn, cs;
            __sincosf(ang, &sn, &cs);
            float2 a = s[i0], b = s[i1];
            float2 tt = make_float2(b.x * cs - b.y * sn, b.x * sn + b.y * cs);
            s[i0] = make_float2(a.x + tt.x, a.y + tt.y);
            s[i1] = make_float2(a.x - tt.x, a.y - tt.y);
        }
        __syncthreads();
    }
}

__global__ __launch_bounds__(64) void fft_rows_fwd(const float* __restrict__ pred,
                                                   float2* __restrict__ out)
{
    __shared__ float2 s[256];
    int row = blockIdx.x, tid = threadIdx.x;
    const float* p = pred + (size_t)row * 256;
    for (int i = tid; i < 256; i += 64) s[i] = make_float2(p[i], 0.f);
    fft256(s, tid, -1.f);
    float2* o = out + (size_t)row * 256;
    for (int i = tid; i < 256; i += 64) o[i] = s[i];
}

__global__ __launch_bounds__(64) void fft_cols_combine(float2* __restrict__ data,
                                                       const float* __restrict__ ksp,
                                                       const float* __restrict__ mask)
{
    __shared__ float2 s[256];
    int col = blockIdx.x & 255, b = blockIdx.x >> 8;
    int tid = threadIdx.x;
    float2* base = data + (size_t)b * 65536 + col;
    for (int i = tid; i < 256; i += 64) s[i] = base[(size_t)i * 256];
    fft256(s, tid, -1.f);
    for (int i = tid; i < 256; i += 64) {
        size_t mi = ((size_t)b * 256 + i) * 256 + col;
        float m = mask[mi];
        float2 kp = s[i];
        float kr = ksp[mi * 2], ki = ksp[mi * 2 + 1];
        s[i] = make_float2(m * kr + (1.f - m) * kp.x * (1.f / 256.f),
                           m * ki + (1.f - m) * kp.y * (1.f / 256.f));
    }
    fft256(s, tid, 1.f);
    for (int i = tid; i < 256; i += 64) base[(size_t)i * 256] = s[i];
}

__global__ __launch_bounds__(64) void fft_rows_inv(const float2* __restrict__ data,
                                                   float* __restrict__ out)
{
    __shared__ float2 s[256];
    int row = blockIdx.x, tid = threadIdx.x;
    const float2* p = data + (size_t)row * 256;
    for (int i = tid; i < 256; i += 64) s[i] = p[i];
    fft256(s, tid, 1.f);
    float* o = out + (size_t)row * 256;
    for (int i = tid; i < 256; i += 64) o[i] = s[i].x * (1.f / 256.f);
}

// ---------------------------------------------------------------------------
extern "C" void kernel_launch(void* const* d_in, const int* in_sizes, int n_in,
                              void* d_out, int out_size, void* d_ws, size_t ws_size,
                              hipStream_t stream)
{
    (void)in_sizes; (void)n_in; (void)out_size; (void)ws_size;

    const float* x0 = (const float*)d_in[0];
    const float* ksp = (const float*)d_in[1];
    const float* mask = (const float*)d_in[2];
    const float* mod_d[4] = {(const float*)d_in[3], (const float*)d_in[6],
                             (const float*)d_in[9], (const float*)d_in[12]};
    const float* W_d[4] = {(const float*)d_in[4], (const float*)d_in[7],
                           (const float*)d_in[10], (const float*)d_in[13]};
    const float* mod_lat = (const float*)d_in[15];
    const float* W_lat = (const float*)d_in[16];
    const float* mod_u[4] = {(const float*)d_in[18], (const float*)d_in[21],
                             (const float*)d_in[24], (const float*)d_in[27]};
    const float* W_u[4] = {(const float*)d_in[19], (const float*)d_in[22],
                           (const float*)d_in[25], (const float*)d_in[28]};
    const float* w_c1 = (const float*)d_in[30];
    const float* b_c1 = (const float*)d_in[31];
    const float* w_c2 = (const float*)d_in[32];
    const float* b_c2 = (const float*)d_in[33];
    const float* w_c3 = (const float*)d_in[34];
    const float* b_c3 = (const float*)d_in[35];

    // ---- workspace layout (CL bf16 activations), ~146 MB
    short* sA  = (short*)d_ws;          // 16,777,216
    short* sB  = sA + 16777216;         // 16,777,216
    short* sk0 = sB + 16777216;         // 16,777,216 (8,256,256,32)
    short* sk1 = sk0 + 16777216;        //  8,388,608 (8,128,128,64)
    short* sk2 = sk1 + 8388608;         //  4,194,304 (8,64,64,128)
    short* sk3 = sk2 + 4194304;         //  2,097,152 (8,32,32,256)
    short* wm  = sk3 + 2097152;         //  4,718,592 (JIT wm scratch)
    float* pred = (float*)(wm + 4718592);      // 524,288
    float2* cplx = (float2*)(pred + 524288);   // 524,288 float2
    float2* stA = cplx + 524288;               // 7,936 float2 stat accumulators
    float* eff = (float*)(stA + 7936);         // 64

    // per-layer stat slices (float2 offsets)
    float2* st_d0 = stA + 0;
    float2* st_d1 = stA + 256;
    float2* st_d2 = stA + 768;
    float2* st_d3 = stA + 1792;
    float2* st_lat = stA + 3840;
    float2* st_u0 = stA + 5888;
    float2* st_u1 = stA + 6912;
    float2* st_u2 = stA + 7424;
    float2* st_u3 = stA + 7680;

    dim3 blk(256);

    zero_f<<<62, blk, 0, stream>>>((float*)stA, 15872);
    eff1x1<<<1, 64, 0, stream>>>(w_c1, b_c1, w_c2, b_c2, w_c3, b_c3, eff);

    // ---- down 0: 1 -> 32 @256
    conv_d0_cl<<<dim3(256, 8), blk, 0, stream>>>(x0, W_d[0], mod_d[0], sk0, st_d0);
    norm_relu_cl<<<dim3(512, 8), blk, 0, stream>>>(sk0, st_d0, 32, 262144, 1.f / 65536.f);
    maxpool_cl<<<2048, blk, 0, stream>>>(sk0, sA, 2, 7, 7, 524288);

    // ---- down 1: 32 -> 64 @128
    make_wm<<<(8 * 64 * 32 + 255) / 256, blk, 0, stream>>>(W_d[1], mod_d[1], wm, 64, 32);
    conv3x3_cl<4, 4><<<dim3(64, 1, 8), blk, 0, stream>>>(sA, 32, sA, wm, sk1, st_d1, 32, 64, 128, 128);
    norm_relu_cl<<<dim3(256, 8), blk, 0, stream>>>(sk1, st_d1, 64, 131072, 1.f / 16384.f);
    maxpool_cl<<<1024, blk, 0, stream>>>(sk1, sA, 3, 6, 6, 262144);

    // ---- down 2: 64 -> 128 @64
    make_wm<<<(8 * 128 * 64 + 255) / 256, blk, 0, stream>>>(W_d[2], mod_d[2], wm, 128, 64);
    conv3x3_cl<2, 4><<<dim3(32, 2, 8), blk, 0, stream>>>(sA, 64, sA, wm, sk2, st_d2, 64, 128, 64, 64);
    norm_relu_cl<<<dim3(128, 8), blk, 0, stream>>>(sk2, st_d2, 128, 65536, 1.f / 4096.f);
    maxpool_cl<<<512, blk, 0, stream>>>(sk2, sA, 4, 5, 5, 131072);

    // ---- down 3: 128 -> 256 @32
    make_wm<<<(8 * 256 * 128 + 255) / 256, blk, 0, stream>>>(W_d[3], mod_d[3], wm, 256, 128);
    conv3x3_cl<2, 2><<<dim3(8, 8, 8), blk, 0, stream>>>(sA, 128, sA, wm, sk3, st_d3, 128, 256, 32, 32);
    norm_relu_cl<<<dim3(64, 8), blk, 0, stream>>>(sk3, st_d3, 256, 32768, 1.f / 1024.f);
    maxpool_cl<<<256, blk, 0, stream>>>(sk3, sA, 5, 4, 4, 65536);

    // ---- latent: 256 -> 256 @16
    make_wm<<<(8 * 256 * 256 + 255) / 256, blk, 0, stream>>>(W_lat, mod_lat, wm, 256, 256);
    conv3x3_cl<2, 1><<<dim3(2, 16, 8), blk, 0, stream>>>(sA, 256, sA, wm, sB, st_lat, 256, 256, 16, 16);
    norm_relu_cl<<<dim3(32, 8), blk, 0, stream>>>(sB, st_lat, 256, 8192, 1.f / 256.f);

    // ---- up 0: up(256@16->32) ++ sk3(256) -> 128 @32
    upsample_cl<<<1024, blk, 0, stream>>>(sB, sA, 5, 4, 4, 262144);
    make_wm<<<(8 * 128 * 512 + 255) / 256, blk, 0, stream>>>(W_u[0], mod_u[0], wm, 128, 512);
    conv3x3_cl<2, 1><<<dim3(8, 8, 8), blk, 0, stream>>>(sA, 256, sk3, wm, sB, st_u0, 512, 128, 32, 32);
    norm_relu_cl<<<dim3(32, 8), blk, 0, stream>>>(sB, st_u0, 128, 16384, 1.f / 1024.f);

    // ---- up 1: up(128@32->64) ++ sk2(128) -> 64 @64
    upsample_cl<<<2048, blk, 0, stream>>>(sB, sA, 4, 5, 5, 524288);
    make_wm<<<(8 * 64 * 256 + 255) / 256, blk, 0, stream>>>(W_u[1], mod_u[1], wm, 64, 256);
    conv3x3_cl<2, 2><<<dim3(32, 2, 8), blk, 0, stream>>>(sA, 128, sk2, wm, sB, st_u1, 256, 64, 64, 64);
    norm_relu_cl<<<dim3(64, 8), blk, 0, stream>>>(sB, st_u1, 64, 32768, 1.f / 4096.f);

    // ---- up 2: up(64@64->128) ++ sk1(64) -> 32 @128
    upsample_cl<<<4096, blk, 0, stream>>>(sB, sA, 3, 6, 6, 1048576);
    make_wm<<<(8 * 32 * 128 + 255) / 256, blk, 0, stream>>>(W_u[2], mod_u[2], wm, 32, 128);
    conv3x3_cl<4, 2><<<dim3(64, 1, 8), blk, 0, stream>>>(sA, 64, sk1, wm, sB, st_u2, 128, 32, 128, 128);
    norm_relu_cl<<<dim3(128, 8), blk, 0, stream>>>(sB, st_u2, 32, 65536, 1.f / 16384.f);

    // ---- up 3: up(32@128->256) ++ sk0(32) -> 32 @256
    upsample_cl<<<8192, blk, 0, stream>>>(sB, sA, 2, 7, 7, 2097152);
    make_wm<<<(8 * 32 * 64 + 255) / 256, blk, 0, stream>>>(W_u[3], mod_u[3], wm, 32, 64);
    conv3x3_cl<4, 2><<<dim3(256, 1, 8), blk, 0, stream>>>(sA, 32, sk0, wm, sB, st_u3, 64, 32, 256, 256);
    norm_relu_cl<<<dim3(512, 8), blk, 0, stream>>>(sB, st_u3, 32, 262144, 1.f / 65536.f);

    // ---- fused 1x1 chain + residual
    final_pred_cl<<<2048, blk, 0, stream>>>(sB, x0, eff, pred);

    // ---- FFT data consistency
    fft_rows_fwd<<<2048, 64, 0, stream>>>(pred, cplx);
    fft_cols_combine<<<2048, 64, 0, stream>>>(cplx, ksp, mask);
    fft_rows_inv<<<2048, 64, 0, stream>>>(cplx, (float*)d_out);
}